// Round 5
// baseline (152.757 us; speedup 1.0000x reference)
//
#include <hip/hip_runtime.h>

#define NB   2
#define NCO  8
#define NCI  8
#define ND   8
#define NGH  16
#define NGW  16
#define NH   512
#define NW   512
#define STRIDE 132   // LDS row stride (floats): 128 data + 4 pad (keeps 16B align, kills conflicts)

// One 512-thread block per (b, image_row). All pixels share y -> cy, wy uniform:
// grid is y-interpolated into LDS at staging (R[gx][co][k][z], bias pre-scaled 1/8).
// All global loads/stores perfectly coalesced; epilogue LDS reads are near-broadcast.
__global__ __launch_bounds__(512, 8) void bslice_kernel(
    const float* __restrict__ grid,
    const float* __restrict__ guide,
    const float* __restrict__ inp,
    float* __restrict__ out)
{
    const int tid = threadIdx.x;          // 0..511 = x
    const int py  = blockIdx.x;           // 0..511 = y
    const int b   = blockIdx.y;           // 0..1

    const float step = (float)(NGH - 1) / (float)(NH - 1);   // 15/511
    const float yp = (float)py * step;
    const int   cy = min((int)yp, NGH - 2);
    const float wy = yp - (float)cy;

    // Stage y-interpolated grid: sg[gx*STRIDE + co*16 + k*8 + z]
    __shared__ float sg[NGW * STRIDE];
    for (int i = tid; i < NGW * 128; i += 512) {
        int gx = i & 15;
        int z  = (i >> 4) & 7;
        int k  = (i >> 7) & 1;
        int co = i >> 8;
        const float* gp = grid + ((((size_t)(b * NCO + co) * 2 + k) * ND + z) * NGH + cy) * NGW + gx;
        float g0 = gp[0];
        float g1 = gp[NGW];
        float v  = g0 * (1.f - wy) + g1 * wy;
        if (k) v *= 0.125f;                 // fold bias mean (1/8)
        sg[gx * STRIDE + co * 16 + k * 8 + z] = v;
    }
    __syncthreads();

    const int px = tid;
    const float xp = (float)px * step;
    const int   cx = min((int)xp, NGW - 2);
    const float wx = xp - (float)cx;

    const int off = py * NW + px;
    const size_t inbase = (size_t)b * NCI * NH * NW;

    // z-tent accumulators: S0[z] = sum_ci tent_z*inp, S1[z] = sum_ci tent_z.
    float S0[8], S1[8];
    #pragma unroll
    for (int z = 0; z < 8; ++z) { S0[z] = 0.f; S1[z] = 0.f; }

    const float* gp = guide + inbase + off;
    const float* vp = inp   + inbase + off;
    #pragma unroll
    for (int ci = 0; ci < NCI; ++ci) {
        float g = gp[(size_t)ci * NH * NW];
        float v = vp[(size_t)ci * NH * NW];
        float zp = fminf(fmaxf(g * 7.0f, 0.0f), 7.0f);
        #pragma unroll
        for (int z = 0; z < 8; ++z) {
            float a = fmaxf(0.0f, 1.0f - fabsf(zp - (float)z));
            S0[z] = fmaf(a, v, S0[z]);
            S1[z] += a;
        }
    }

    const size_t obase = (size_t)b * NCO * NH * NW;
    const float* col0 = &sg[cx * STRIDE];
    const float* col1 = col0 + STRIDE;

    #pragma unroll 1
    for (int co = 0; co < NCO; ++co) {
        // column cx: [W z0..7 | B/8 z0..7], 16 floats, 16B-aligned
        const float4 a0 = *(const float4*)(col0 + co * 16 + 0);
        const float4 a1 = *(const float4*)(col0 + co * 16 + 4);
        const float4 a2 = *(const float4*)(col0 + co * 16 + 8);
        const float4 a3 = *(const float4*)(col0 + co * 16 + 12);
        const float4 b0 = *(const float4*)(col1 + co * 16 + 0);
        const float4 b1 = *(const float4*)(col1 + co * 16 + 4);
        const float4 b2 = *(const float4*)(col1 + co * 16 + 8);
        const float4 b3 = *(const float4*)(col1 + co * 16 + 12);

        float t0, t1;
        t0 = S0[0] * a0.x;                 t1 = S0[0] * b0.x;
        t0 = fmaf(S0[1], a0.y, t0);        t1 = fmaf(S0[1], b0.y, t1);
        t0 = fmaf(S0[2], a0.z, t0);        t1 = fmaf(S0[2], b0.z, t1);
        t0 = fmaf(S0[3], a0.w, t0);        t1 = fmaf(S0[3], b0.w, t1);
        t0 = fmaf(S0[4], a1.x, t0);        t1 = fmaf(S0[4], b1.x, t1);
        t0 = fmaf(S0[5], a1.y, t0);        t1 = fmaf(S0[5], b1.y, t1);
        t0 = fmaf(S0[6], a1.z, t0);        t1 = fmaf(S0[6], b1.z, t1);
        t0 = fmaf(S0[7], a1.w, t0);        t1 = fmaf(S0[7], b1.w, t1);
        t0 = fmaf(S1[0], a2.x, t0);        t1 = fmaf(S1[0], b2.x, t1);
        t0 = fmaf(S1[1], a2.y, t0);        t1 = fmaf(S1[1], b2.y, t1);
        t0 = fmaf(S1[2], a2.z, t0);        t1 = fmaf(S1[2], b2.z, t1);
        t0 = fmaf(S1[3], a2.w, t0);        t1 = fmaf(S1[3], b2.w, t1);
        t0 = fmaf(S1[4], a3.x, t0);        t1 = fmaf(S1[4], b3.x, t1);
        t0 = fmaf(S1[5], a3.y, t0);        t1 = fmaf(S1[5], b3.y, t1);
        t0 = fmaf(S1[6], a3.z, t0);        t1 = fmaf(S1[6], b3.z, t1);
        t0 = fmaf(S1[7], a3.w, t0);        t1 = fmaf(S1[7], b3.w, t1);

        out[obase + (size_t)co * NH * NW + off] = (1.f - wx) * t0 + wx * t1;
    }
}

extern "C" void kernel_launch(void* const* d_in, const int* in_sizes, int n_in,
                              void* d_out, int out_size, void* d_ws, size_t ws_size,
                              hipStream_t stream) {
    const float* grid  = (const float*)d_in[0];
    const float* guide = (const float*)d_in[1];
    const float* inp   = (const float*)d_in[2];
    float* out = (float*)d_out;

    dim3 g(NH, NB);   // (512 rows, 2 batches) = 1024 blocks x 8 waves
    bslice_kernel<<<g, 512, 0, stream>>>(grid, guide, inp, out);
}

// Round 6
// 91.155 us; speedup vs baseline: 1.6758x; 1.6758x over previous
//
#include <hip/hip_runtime.h>

#define NB   2
#define NCO  8
#define NCI  8
#define ND   8
#define NGH  16
#define NGW  16
#define NH   512
#define NW   512
#define STRIDE 132   // LDS row stride (floats): 128 data + 4 pad (16B-aligned, conflict-free)

// One 512-thread block per (b, image_row). All pixels share y -> cy, wy uniform:
// grid is y-interpolated into LDS at staging (sg[gx][co][k][z], bias pre-scaled 1/8).
// Global loads/stores perfectly coalesced; epilogue LDS reads are near-broadcast
// (<=3 distinct cx per wave).
// launch_bounds(512,4): VGPR cap 128. (512,8) capped at 32 VGPR -> scratch spills
// were the entire R4/R5 regression (FETCH 193MB/WRITE 126MB of spill traffic).
__global__ __launch_bounds__(512, 4) void bslice_kernel(
    const float* __restrict__ grid,
    const float* __restrict__ guide,
    const float* __restrict__ inp,
    float* __restrict__ out)
{
    const int tid = threadIdx.x;          // 0..511 = x
    const int py  = blockIdx.x;           // 0..511 = y
    const int b   = blockIdx.y;           // 0..1

    const float step = (float)(NGH - 1) / (float)(NH - 1);   // 15/511
    const float yp = (float)py * step;
    const int   cy = min((int)yp, NGH - 2);
    const float wy = yp - (float)cy;

    // Stage y-interpolated grid: sg[gx*STRIDE + co*16 + k*8 + z]
    __shared__ float sg[NGW * STRIDE];
    for (int i = tid; i < NGW * 128; i += 512) {
        int gx = i & 15;
        int z  = (i >> 4) & 7;
        int k  = (i >> 7) & 1;
        int co = i >> 8;
        const float* gp = grid + ((((size_t)(b * NCO + co) * 2 + k) * ND + z) * NGH + cy) * NGW + gx;
        float g0 = gp[0];
        float g1 = gp[NGW];
        float v  = g0 * (1.f - wy) + g1 * wy;
        if (k) v *= 0.125f;                 // fold bias mean (1/8)
        sg[gx * STRIDE + co * 16 + k * 8 + z] = v;
    }
    __syncthreads();

    const int px = tid;
    const float xp = (float)px * step;
    const int   cx = min((int)xp, NGW - 2);
    const float wx = xp - (float)cx;

    const int off = py * NW + px;
    const size_t inbase = (size_t)b * NCI * NH * NW;

    // z-tent accumulators: S0[z] = sum_ci tent_z*inp, S1[z] = sum_ci tent_z.
    float S0[8], S1[8];
    #pragma unroll
    for (int z = 0; z < 8; ++z) { S0[z] = 0.f; S1[z] = 0.f; }

    const float* gp = guide + inbase + off;
    const float* vp = inp   + inbase + off;
    #pragma unroll
    for (int ci = 0; ci < NCI; ++ci) {
        float g = gp[(size_t)ci * NH * NW];
        float v = vp[(size_t)ci * NH * NW];
        float zp = fminf(fmaxf(g * 7.0f, 0.0f), 7.0f);
        #pragma unroll
        for (int z = 0; z < 8; ++z) {
            float a = fmaxf(0.0f, 1.0f - fabsf(zp - (float)z));
            S0[z] = fmaf(a, v, S0[z]);
            S1[z] += a;
        }
    }

    const size_t obase = (size_t)b * NCO * NH * NW;
    const float* col0 = &sg[cx * STRIDE];
    const float* col1 = col0 + STRIDE;

    #pragma unroll 1
    for (int co = 0; co < NCO; ++co) {
        // column cx: [W z0..7 | B/8 z0..7], 16 floats, 16B-aligned.
        // Process col0 fully, then col1 -> peak live LDS-read regs = 16 not 32.
        float t0, t1;
        {
            const float4 a0 = *(const float4*)(col0 + co * 16 + 0);
            const float4 a1 = *(const float4*)(col0 + co * 16 + 4);
            const float4 a2 = *(const float4*)(col0 + co * 16 + 8);
            const float4 a3 = *(const float4*)(col0 + co * 16 + 12);
            t0 = S0[0] * a0.x;
            t0 = fmaf(S0[1], a0.y, t0);
            t0 = fmaf(S0[2], a0.z, t0);
            t0 = fmaf(S0[3], a0.w, t0);
            t0 = fmaf(S0[4], a1.x, t0);
            t0 = fmaf(S0[5], a1.y, t0);
            t0 = fmaf(S0[6], a1.z, t0);
            t0 = fmaf(S0[7], a1.w, t0);
            t0 = fmaf(S1[0], a2.x, t0);
            t0 = fmaf(S1[1], a2.y, t0);
            t0 = fmaf(S1[2], a2.z, t0);
            t0 = fmaf(S1[3], a2.w, t0);
            t0 = fmaf(S1[4], a3.x, t0);
            t0 = fmaf(S1[5], a3.y, t0);
            t0 = fmaf(S1[6], a3.z, t0);
            t0 = fmaf(S1[7], a3.w, t0);
        }
        {
            const float4 b0 = *(const float4*)(col1 + co * 16 + 0);
            const float4 b1 = *(const float4*)(col1 + co * 16 + 4);
            const float4 b2 = *(const float4*)(col1 + co * 16 + 8);
            const float4 b3 = *(const float4*)(col1 + co * 16 + 12);
            t1 = S0[0] * b0.x;
            t1 = fmaf(S0[1], b0.y, t1);
            t1 = fmaf(S0[2], b0.z, t1);
            t1 = fmaf(S0[3], b0.w, t1);
            t1 = fmaf(S0[4], b1.x, t1);
            t1 = fmaf(S0[5], b1.y, t1);
            t1 = fmaf(S0[6], b1.z, t1);
            t1 = fmaf(S0[7], b1.w, t1);
            t1 = fmaf(S1[0], b2.x, t1);
            t1 = fmaf(S1[1], b2.y, t1);
            t1 = fmaf(S1[2], b2.z, t1);
            t1 = fmaf(S1[3], b2.w, t1);
            t1 = fmaf(S1[4], b3.x, t1);
            t1 = fmaf(S1[5], b3.y, t1);
            t1 = fmaf(S1[6], b3.z, t1);
            t1 = fmaf(S1[7], b3.w, t1);
        }
        out[obase + (size_t)co * NH * NW + off] = (1.f - wx) * t0 + wx * t1;
    }
}

extern "C" void kernel_launch(void* const* d_in, const int* in_sizes, int n_in,
                              void* d_out, int out_size, void* d_ws, size_t ws_size,
                              hipStream_t stream) {
    const float* grid  = (const float*)d_in[0];
    const float* guide = (const float*)d_in[1];
    const float* inp   = (const float*)d_in[2];
    float* out = (float*)d_out;

    dim3 g(NH, NB);   // (512 rows, 2 batches) = 1024 blocks x 8 waves
    bslice_kernel<<<g, 512, 0, stream>>>(grid, guide, inp, out);
}